// Round 4
// baseline (1117.247 us; speedup 1.0000x reference)
//
#include <hip/hip_runtime.h>
#include <hip/hip_cooperative_groups.h>
#include <hip/hip_bf16.h>
#include <math.h>

#define SEQ   2048
#define H     1024
#define VOCAB 32000
#define GRID  2048
#define NTHR  256

namespace cg = cooperative_groups;

__device__ inline float4 ld4(const float* p) { return *reinterpret_cast<const float4*>(p); }
__device__ inline float dot4(float4 a, float4 b) { return a.x*b.x + a.y*b.y + a.z*b.z + a.w*b.w; }
__device__ inline float sigmoidf(float x) { return 1.f / (1.f + expf(-x)); }

__device__ inline void omerge(float& m, float& s, float m2, float s2) {
    if (m2 > m) { s = s * __expf(m - m2) + s2; m = m2; }
    else if (s2 != 0.f) { s += s2 * __expf(m2 - m); }
}
__device__ inline float waveSum(float v) {
#pragma unroll
    for (int off = 32; off > 0; off >>= 1) v += __shfl_down(v, off, 64);
    return v;
}
__device__ inline float waveMax(float v) {
#pragma unroll
    for (int off = 32; off > 0; off >>= 1) v = fmaxf(v, __shfl_down(v, off, 64));
    return v;
}
__device__ inline void waveOmerge(float& m, float& s) {
#pragma unroll
    for (int off = 32; off > 0; off >>= 1) {
        float m2 = __shfl_down(m, off, 64), ss = __shfl_down(s, off, 64);
        omerge(m, s, m2, ss);
    }
}

// ======================= cooperative fused kernel ==========================
// GRID=2048 blocks x 256 thr = 8 blocks/CU (VGPR<=64, LDS 8.3KB) -> 32 waves/CU

__global__ __launch_bounds__(NTHR, 8) void kfused(
        const float* __restrict__ emb,  const float* __restrict__ lctx,
        const float* __restrict__ h0,   const float* __restrict__ W_ih,
        const float* __restrict__ W_hh, const float* __restrict__ b_ih,
        const float* __restrict__ b_hh, const int* __restrict__ widx,
        const float* __restrict__ enc,  const float* __restrict__ Wa,
        const float* __restrict__ Wl,   const float* __restrict__ bl,
        float* __restrict__ ws, float* __restrict__ out) {
    cg::grid_group grid = cg::this_grid();
    const int bid = blockIdx.x, t = threadIdx.x;
    const int wid = t >> 6, lane = t & 63;
    const int gw = bid * 4 + wid;               // global wave id 0..8191

    // ws layout (floats): total 9216 floats = 36.9 KB
    float*  vcat   = ws;                        // [2048] = h | ctx
    float*  h      = vcat;
    float*  ctx    = vcat + H;
    float*  u      = ws + 2048;                 // [1024]
    float*  energ  = ws + 3072;                 // [2048]
    float2* part_l = (float2*)(ws + 5120);      // [2048]
    // logits live in out[] (rewritten in place by P6)

    __shared__ __align__(16) float sx[2048];    // 8 KB staging
    __shared__ float  sred[16];
    __shared__ float2 s2[4];

    // ============ P1: LSTM cell — one block per output j ===================
    if (bid < H) {
        const int j = bid;
        const int w = widx[0];                  // int64 LE, value < 32000
        const float* xe = emb + (size_t)w * H;
        const float* wi = W_ih + (size_t)j * (2 * H);
        const float* wg = W_ih + (size_t)(j + 2 * H) * (2 * H);
        const float* wo = W_ih + (size_t)(j + 3 * H) * (2 * H);
        const float* vi = W_hh + (size_t)j * H;
        const float* vg = W_hh + (size_t)(j + 2 * H) * H;
        const float* vo = W_hh + (size_t)(j + 3 * H) * H;
        const int e = t * 4;                    // 0..1020
        float4 x0 = ld4(xe + e), x1 = ld4(lctx + e), x2 = ld4(h0 + e);
        float ai = dot4(ld4(wi + e), x0) + dot4(ld4(wi + H + e), x1) + dot4(ld4(vi + e), x2);
        float ag = dot4(ld4(wg + e), x0) + dot4(ld4(wg + H + e), x1) + dot4(ld4(vg + e), x2);
        float ao = dot4(ld4(wo + e), x0) + dot4(ld4(wo + H + e), x1) + dot4(ld4(vo + e), x2);
        ai = waveSum(ai); ag = waveSum(ag); ao = waveSum(ao);
        if (lane == 0) { sred[wid*3] = ai; sred[wid*3+1] = ag; sred[wid*3+2] = ao; }
        __syncthreads();
        if (t == 0) {
            float gi = 0.f, gg = 0.f, go = 0.f;
            for (int q = 0; q < 4; ++q) { gi += sred[q*3]; gg += sred[q*3+1]; go += sred[q*3+2]; }
            gi += b_ih[j] + b_hh[j];
            gg += b_ih[j + 2*H] + b_hh[j + 2*H];
            go += b_ih[j + 3*H] + b_hh[j + 3*H];
            float c = sigmoidf(gi) * tanhf(gg);  // c0 == 0 -> f-gate dead
            h[j] = sigmoidf(go) * tanhf(c);
        }
    } else if (bid == H) {
        for (int k = t; k < H; k += NTHR) u[k] = 0.f;
    } else if (bid == H + 1) {
        for (int k = t; k < H; k += NTHR) ctx[k] = 0.f;
    }
    grid.sync();  // ---- h, u=0, ctx=0 ----

    // ============ P2: u = Wa^T h (256 blocks, 16 rows x 256 cols each) =====
    if (bid < 256) {
        const int rg = bid >> 2, kb = bid & 3;
        if (t < 16) sx[t] = h[rg * 16 + t];
        __syncthreads();
        const int k = kb * 256 + t;
        float acc = 0.f;
#pragma unroll
        for (int jj = 0; jj < 16; ++jj)
            acc += Wa[(size_t)(rg * 16 + jj) * H + k] * sx[jj];
        atomicAdd(&u[k], acc);
    }
    grid.sync();  // ---- u ----

    // ============ P3: energies — one block per row =========================
    {
        const float* er = enc + (size_t)bid * H;
        const int e = wid * 256 + lane * 4;
        float acc = dot4(ld4(er + e), ld4(u + e));
        acc = waveSum(acc);
        if (lane == 0) sred[wid] = acc;
        __syncthreads();
        if (t == 0) energ[bid] = sred[0] + sred[1] + sred[2] + sred[3];
    }
    grid.sync();  // ---- energ ----

    // ============ P4: context = softmax(energ) @ enc (512 blocks) ==========
    if (bid < 512) {
        // global (M,S) over energ, computed redundantly per block
        float m = -INFINITY, s = 0.f;
#pragma unroll
        for (int q = 0; q < 8; ++q) {
            float v = energ[t + q * 256];
            omerge(m, s, v, 1.f);
        }
        waveOmerge(m, s);
        if (lane == 0) s2[wid] = make_float2(m, s);
        __syncthreads();
        float M = s2[0].x, S = s2[0].y;
#pragma unroll
        for (int q = 1; q < 4; ++q) omerge(M, S, s2[q].x, s2[q].y);
        const float invS = 1.f / S;
        const int rg = bid >> 2, kb = bid & 3;
        __syncthreads();
        if (t < 16) sx[t] = __expf(energ[rg * 16 + t] - M) * invS;
        __syncthreads();
        const int k = kb * 256 + t;
        float acc = 0.f;
#pragma unroll
        for (int jj = 0; jj < 16; ++jj)
            acc += sx[jj] * enc[(size_t)(rg * 16 + jj) * H + k];
        atomicAdd(&ctx[k], acc);
    }
    grid.sync();  // ---- ctx -> vcat ready ----

    // ===== P5: logits = Wl @ vcat + bl (4 rows/wave) + online (max,sumexp) =
    {
        float4* sx4 = (float4*)sx;              // stage vcat (8KB) in LDS
        sx4[t]       = ld4(vcat + t * 4);
        sx4[256 + t] = ld4(vcat + 1024 + t * 4);
        __syncthreads();
        float lm = -INFINITY, ls = 0.f;
#pragma unroll 1
        for (int it = 0; it < 4; ++it) {
            const int row = it * (GRID * 4) + gw;
            if (row < VOCAB) {
                const float* wr = Wl + (size_t)row * (2 * H);
                float acc = 0.f;
#pragma unroll
                for (int q = 0; q < 8; ++q) {
                    const int e = q * 256 + lane * 4;
                    acc += dot4(ld4(wr + e), *(const float4*)(sx + e));
                }
                acc = waveSum(acc);
                if (lane == 0) {
                    float v = acc + bl[row];
                    out[row] = v;                // logits staged in out[]
                    omerge(lm, ls, v, 1.f);
                }
            }
        }
        __syncthreads();
        if (lane == 0) s2[wid] = make_float2(lm, ls);
        __syncthreads();
        if (t == 0) {
            float M = s2[0].x, S = s2[0].y;
            for (int q = 1; q < 4; ++q) omerge(M, S, s2[q].x, s2[q].y);
            part_l[bid] = make_float2(M, S);
        }
    }
    grid.sync();  // ---- logits (in out[]), part_l ----

    // ============ P6: out = logits - logsumexp (125 blocks) ================
    if (bid < 125) {
        float m = -INFINITY, s = 0.f;
#pragma unroll
        for (int q = 0; q < 8; ++q) {
            float2 p = part_l[t + q * 256];
            omerge(m, s, p.x, p.y);
        }
        waveOmerge(m, s);
        if (lane == 0) s2[wid] = make_float2(m, s);
        __syncthreads();
        float M = s2[0].x, S = s2[0].y;
#pragma unroll
        for (int q = 1; q < 4; ++q) omerge(M, S, s2[q].x, s2[q].y);
        const float lse = M + logf(S);
        const int i = bid * 256 + t;            // 125*256 == 32000 exactly
        out[i] = out[i] - lse;
    }
}

// ======================= fallback path (round-1, proven) ===================

__global__ __launch_bounds__(256) void k_lstm(
        const float* __restrict__ emb, const float* __restrict__ lctx,
        const float* __restrict__ h0,  const float* __restrict__ W_ih,
        const float* __restrict__ W_hh, const float* __restrict__ b_ih,
        const float* __restrict__ b_hh, const int* __restrict__ widx,
        float* __restrict__ h_out, float* __restrict__ u_zero) {
    const int j = blockIdx.x, t = threadIdx.x;
    const int wid = t >> 6, lane = t & 63;
    if (j == 0) for (int k = t; k < H; k += 256) u_zero[k] = 0.f;
    const int w = widx[0];
    const float* embrow = emb + (size_t)w * H;
    const int ri = j, rg = j + 2 * H, ro = j + 3 * H;
    const float* wi_i = W_ih + (size_t)ri * (2 * H);
    const float* wi_g = W_ih + (size_t)rg * (2 * H);
    const float* wi_o = W_ih + (size_t)ro * (2 * H);
    const float* wh_i = W_hh + (size_t)ri * H;
    const float* wh_g = W_hh + (size_t)rg * H;
    const float* wh_o = W_hh + (size_t)ro * H;
    float ai = 0.f, ag = 0.f, ao = 0.f;
    { int e = t*4; float4 x = ld4(embrow+e);
      ai += dot4(ld4(wi_i+e),x); ag += dot4(ld4(wi_g+e),x); ao += dot4(ld4(wi_o+e),x); }
    { int e = t*4; float4 x = ld4(lctx+e);
      ai += dot4(ld4(wi_i+H+e),x); ag += dot4(ld4(wi_g+H+e),x); ao += dot4(ld4(wi_o+H+e),x); }
    { int e = t*4; float4 x = ld4(h0+e);
      ai += dot4(ld4(wh_i+e),x); ag += dot4(ld4(wh_g+e),x); ao += dot4(ld4(wh_o+e),x); }
    ai = waveSum(ai); ag = waveSum(ag); ao = waveSum(ao);
    __shared__ float lds[12];
    if (lane == 0) { lds[wid*3] = ai; lds[wid*3+1] = ag; lds[wid*3+2] = ao; }
    __syncthreads();
    if (t == 0) {
        float gi = 0.f, gg = 0.f, go = 0.f;
        for (int q = 0; q < 4; ++q) { gi += lds[q*3]; gg += lds[q*3+1]; go += lds[q*3+2]; }
        gi += b_ih[ri] + b_hh[ri];
        gg += b_ih[rg] + b_hh[rg];
        go += b_ih[ro] + b_hh[ro];
        float c = sigmoidf(gi) * tanhf(gg);
        h_out[j] = sigmoidf(go) * tanhf(c);
    }
}

__global__ __launch_bounds__(256) void k_wa(
        const float* __restrict__ Wa, const float* __restrict__ h,
        float* __restrict__ u) {
    const int k = blockIdx.x * 256 + threadIdx.x;
    const int j0 = blockIdx.y * 32;
    float acc = 0.f;
#pragma unroll 8
    for (int j = j0; j < j0 + 32; ++j) acc += Wa[(size_t)j * H + k] * h[j];
    atomicAdd(&u[k], acc);
}

__global__ __launch_bounds__(256) void k_energy(
        const float* __restrict__ enc, const float* __restrict__ u,
        float* __restrict__ energ) {
    const int wid = threadIdx.x >> 6, lane = threadIdx.x & 63;
    const int row = blockIdx.x * 4 + wid;
    const float* er = enc + (size_t)row * H;
    float acc = 0.f;
#pragma unroll
    for (int it = 0; it < 4; ++it) { int e = it*256 + lane*4; acc += dot4(ld4(er+e), ld4(u+e)); }
    acc = waveSum(acc);
    if (lane == 0) energ[row] = acc;
}

__global__ __launch_bounds__(1024) void k_softmax(
        const float* __restrict__ energ, float* __restrict__ attw,
        float* __restrict__ ctx_zero) {
    const int t = threadIdx.x, wid = t >> 6, lane = t & 63;
    __shared__ float red[16];
    ctx_zero[t] = 0.f;
    float e0 = energ[t], e1 = energ[t + 1024];
    float m = waveMax(fmaxf(e0, e1));
    if (lane == 0) red[wid] = m;
    __syncthreads();
    float M = -1e30f;
    for (int q = 0; q < 16; ++q) M = fmaxf(M, red[q]);
    __syncthreads();
    float x0 = expf(e0 - M), x1 = expf(e1 - M);
    float s = waveSum(x0 + x1);
    if (lane == 0) red[wid] = s;
    __syncthreads();
    float S = 0.f;
    for (int q = 0; q < 16; ++q) S += red[q];
    attw[t] = x0 / S; attw[t + 1024] = x1 / S;
}

__global__ __launch_bounds__(256) void k_context(
        const float* __restrict__ enc, const float* __restrict__ attw,
        float* __restrict__ ctx) {
    const int k = (blockIdx.x & 3) * 256 + threadIdx.x;
    const int j0 = (blockIdx.x >> 2) * 64;
    float acc = 0.f;
#pragma unroll 8
    for (int j = j0; j < j0 + 64; ++j) acc += attw[j] * enc[(size_t)j * H + k];
    atomicAdd(&ctx[k], acc);
}

__global__ __launch_bounds__(256) void k_logits(
        const float* __restrict__ Wl, const float* __restrict__ vcat,
        const float* __restrict__ bl, float* __restrict__ logits) {
    const int wid = threadIdx.x >> 6, lane = threadIdx.x & 63;
    const int row = blockIdx.x * 4 + wid;
    const float* wr = Wl + (size_t)row * (2 * H);
    float acc = 0.f;
#pragma unroll
    for (int it = 0; it < 8; ++it) { int e = it*256 + lane*4; acc += dot4(ld4(wr+e), ld4(vcat+e)); }
    acc = waveSum(acc);
    if (lane == 0) logits[row] = acc + bl[row];
}

__global__ __launch_bounds__(1024) void k_logsoftmax(
        const float* __restrict__ logits, float* __restrict__ out) {
    const int t = threadIdx.x, wid = t >> 6, lane = t & 63;
    __shared__ float red[16];
    float m = -1e30f;
    for (int i = t; i < VOCAB; i += 1024) m = fmaxf(m, logits[i]);
    m = waveMax(m);
    if (lane == 0) red[wid] = m;
    __syncthreads();
    float M = -1e30f;
    for (int q = 0; q < 16; ++q) M = fmaxf(M, red[q]);
    __syncthreads();
    float s = 0.f;
    for (int i = t; i < VOCAB; i += 1024) s += expf(logits[i] - M);
    s = waveSum(s);
    if (lane == 0) red[wid] = s;
    __syncthreads();
    float S = 0.f;
    for (int q = 0; q < 16; ++q) S += red[q];
    const float lse = M + logf(S);
    for (int i = t; i < VOCAB; i += 1024) out[i] = logits[i] - lse;
}

extern "C" void kernel_launch(void* const* d_in, const int* in_sizes, int n_in,
                              void* d_out, int out_size, void* d_ws, size_t ws_size,
                              hipStream_t stream) {
    const int*   widx = (const int*)d_in[0];
    const float* lctx = (const float*)d_in[1];
    const float* h0   = (const float*)d_in[2];
    const float* enc  = (const float*)d_in[3];
    const float* emb  = (const float*)d_in[4];
    const float* W_ih = (const float*)d_in[5];
    const float* W_hh = (const float*)d_in[6];
    const float* b_ih = (const float*)d_in[7];
    const float* b_hh = (const float*)d_in[8];
    const float* Wa   = (const float*)d_in[9];
    // d_in[10] (ba): dropped — constant shift under softmax
    const float* Wl   = (const float*)d_in[11];
    const float* bl   = (const float*)d_in[12];
    float* out = (float*)d_out;
    float* ws  = (float*)d_ws;

    void* args[] = { (void*)&emb, (void*)&lctx, (void*)&h0, (void*)&W_ih,
                     (void*)&W_hh, (void*)&b_ih, (void*)&b_hh, (void*)&widx,
                     (void*)&enc, (void*)&Wa, (void*)&Wl, (void*)&bl,
                     (void*)&ws, (void*)&out };
    hipError_t err = hipLaunchCooperativeKernel((const void*)kfused, dim3(GRID),
                                                dim3(NTHR), args, 0, stream);
    if (err != hipSuccess) {
        // deterministic fallback: proven multi-kernel path
        float* h      = ws;
        float* ctx    = ws + 1024;
        float* u      = ws + 2048;
        float* energ  = ws + 3072;
        float* attw   = ws + 5120;
        float* logits = ws + 7168;
        k_lstm<<<1024, 256, 0, stream>>>(emb, lctx, h0, W_ih, W_hh, b_ih, b_hh, widx, h, u);
        k_wa<<<dim3(4, 32), 256, 0, stream>>>(Wa, h, u);
        k_energy<<<512, 256, 0, stream>>>(enc, u, energ);
        k_softmax<<<1, 1024, 0, stream>>>(energ, attw, ctx);
        k_context<<<128, 256, 0, stream>>>(enc, attw, ctx);
        k_logits<<<8000, 256, 0, stream>>>(Wl, ws /*vcat*/, bl, logits);
        k_logsoftmax<<<1, 1024, 0, stream>>>(logits, out);
    }
}

// Round 5
// 74.825 us; speedup vs baseline: 14.9315x; 14.9315x over previous
//
#include <hip/hip_runtime.h>
#include <hip/hip_bf16.h>
#include <math.h>

#define SEQ   2048
#define H     1024
#define VOCAB 32000

__device__ inline float4 ld4(const float* p) { return *reinterpret_cast<const float4*>(p); }
__device__ inline float dot4(float4 a, float4 b) { return a.x*b.x + a.y*b.y + a.z*b.z + a.w*b.w; }
__device__ inline float sigmoidf(float x) { return 1.f / (1.f + expf(-x)); }

__device__ inline void omerge(float& m, float& s, float m2, float s2) {
    if (m2 > m) { s = s * __expf(m - m2) + s2; m = m2; }
    else if (s2 != 0.f) { s += s2 * __expf(m2 - m); }
}
__device__ inline float waveSum(float v) {
#pragma unroll
    for (int off = 32; off > 0; off >>= 1) v += __shfl_down(v, off, 64);
    return v;
}
__device__ inline void waveOmerge(float& m, float& s) {
#pragma unroll
    for (int off = 32; off > 0; off >>= 1) {
        float m2 = __shfl_down(m, off, 64), ss = __shfl_down(s, off, 64);
        omerge(m, s, m2, ss);
    }
}

// ============ K1: LSTM cell — one block per output j; f-gate dead ==========
__global__ __launch_bounds__(256) void k_lstm(
        const float* __restrict__ emb, const float* __restrict__ lctx,
        const float* __restrict__ h0,  const float* __restrict__ W_ih,
        const float* __restrict__ W_hh, const float* __restrict__ b_ih,
        const float* __restrict__ b_hh, const int* __restrict__ widx,
        float* __restrict__ h_out, float* __restrict__ u_zero,
        float* __restrict__ ctx_zero) {
    const int j = blockIdx.x, t = threadIdx.x;
    const int wid = t >> 6, lane = t & 63;
    if (j == 0) for (int k = t; k < H; k += 256) u_zero[k] = 0.f;
    if (j == 1) for (int k = t; k < H; k += 256) ctx_zero[k] = 0.f;

    const int w = widx[0];                       // int64 LE, value < 32000
    const float* embrow = emb + (size_t)w * H;
    const int ri = j, rg = j + 2 * H, ro = j + 3 * H;
    const float* wi_i = W_ih + (size_t)ri * (2 * H);
    const float* wi_g = W_ih + (size_t)rg * (2 * H);
    const float* wi_o = W_ih + (size_t)ro * (2 * H);
    const float* wh_i = W_hh + (size_t)ri * H;
    const float* wh_g = W_hh + (size_t)rg * H;
    const float* wh_o = W_hh + (size_t)ro * H;

    float ai = 0.f, ag = 0.f, ao = 0.f;
    { int e = t*4; float4 x = ld4(embrow+e);
      ai += dot4(ld4(wi_i+e),x); ag += dot4(ld4(wi_g+e),x); ao += dot4(ld4(wi_o+e),x); }
    { int e = t*4; float4 x = ld4(lctx+e);
      ai += dot4(ld4(wi_i+H+e),x); ag += dot4(ld4(wi_g+H+e),x); ao += dot4(ld4(wi_o+H+e),x); }
    { int e = t*4; float4 x = ld4(h0+e);
      ai += dot4(ld4(wh_i+e),x); ag += dot4(ld4(wh_g+e),x); ao += dot4(ld4(wh_o+e),x); }
    ai = waveSum(ai); ag = waveSum(ag); ao = waveSum(ao);
    __shared__ float lds[12];
    if (lane == 0) { lds[wid*3] = ai; lds[wid*3+1] = ag; lds[wid*3+2] = ao; }
    __syncthreads();
    if (t == 0) {
        float gi = 0.f, gg = 0.f, go = 0.f;
        for (int q = 0; q < 4; ++q) { gi += lds[q*3]; gg += lds[q*3+1]; go += lds[q*3+2]; }
        gi += b_ih[ri] + b_hh[ri];
        gg += b_ih[rg] + b_hh[rg];
        go += b_ih[ro] + b_hh[ro];
        float c = sigmoidf(gi) * tanhf(gg);      // c0 == 0 -> f-gate dead
        h_out[j] = sigmoidf(go) * tanhf(c);
    }
}

// ============ K2: u = Wa^T h (atomics, contention 32) ======================
__global__ __launch_bounds__(256) void k_wa(
        const float* __restrict__ Wa, const float* __restrict__ h,
        float* __restrict__ u) {
    const int k = blockIdx.x * 256 + threadIdx.x;     // gridDim.x = 4
    const int j0 = blockIdx.y * 32;                   // gridDim.y = 32
    float acc = 0.f;
#pragma unroll 8
    for (int j = j0; j < j0 + 32; ++j) acc += Wa[(size_t)j * H + k] * h[j];
    atomicAdd(&u[k], acc);
}

// ============ K3: energies (1 wave/row) + per-block (m,s) partial ==========
__global__ __launch_bounds__(256) void k_energy(
        const float* __restrict__ enc, const float* __restrict__ u,
        float* __restrict__ energ, float2* __restrict__ part_e) {
    const int t = threadIdx.x, wid = t >> 6, lane = t & 63;
    const int row = blockIdx.x * 4 + wid;             // grid 512 -> 2048 rows
    const float* er = enc + (size_t)row * H;
    float acc = 0.f;
#pragma unroll
    for (int it = 0; it < 4; ++it) { int e = it*256 + lane*4; acc += dot4(ld4(er+e), ld4(u+e)); }
    acc = waveSum(acc);
    __shared__ float se[4];
    if (lane == 0) { energ[row] = acc; se[wid] = acc; }
    __syncthreads();
    if (t == 0) {
        float m = fmaxf(fmaxf(se[0], se[1]), fmaxf(se[2], se[3]));
        float s = __expf(se[0]-m) + __expf(se[1]-m) + __expf(se[2]-m) + __expf(se[3]-m);
        part_e[blockIdx.x] = make_float2(m, s);
    }
}

// ============ K4: ctx = softmax(energ) @ enc (redundant partial reduce) ====
__global__ __launch_bounds__(256) void k_ctx(
        const float* __restrict__ enc, const float* __restrict__ energ,
        const float2* __restrict__ part_e, float* __restrict__ ctx) {
    const int t = threadIdx.x, wid = t >> 6, lane = t & 63;
    __shared__ float2 s2[4];
    __shared__ float sh[64];

    // reduce part_e[512] redundantly; all threads get (M,S)
    float2 a = part_e[t], b = part_e[t + 256];
    float m = a.x, s = a.y;
    omerge(m, s, b.x, b.y);
    waveOmerge(m, s);
    if (lane == 0) s2[wid] = make_float2(m, s);
    __syncthreads();
    float M = s2[0].x, S = s2[0].y;
#pragma unroll
    for (int q = 1; q < 4; ++q) omerge(M, S, s2[q].x, s2[q].y);
    const float invS = 1.f / S;

    const int j0 = (blockIdx.x >> 2) * 64;            // grid 128: 32 rowgroups x 4 kslices
    __syncthreads();
    if (t < 64) sh[t] = __expf(energ[j0 + t] - M) * invS;
    __syncthreads();
    const int k = (blockIdx.x & 3) * 256 + t;
    float acc = 0.f;
#pragma unroll 8
    for (int jj = 0; jj < 64; ++jj) acc += sh[jj] * enc[(size_t)(j0 + jj) * H + k];
    atomicAdd(&ctx[k], acc);
}

// ===== K5: logits = Wl@vcat + bl (4 rows/wave, vcat in regs) + partials ====
__global__ __launch_bounds__(256) void k_logits(
        const float* __restrict__ Wl, const float* __restrict__ vcat,
        const float* __restrict__ bl, float* __restrict__ logits,
        float2* __restrict__ part_l) {
    const int t = threadIdx.x, wid = t >> 6, lane = t & 63;
    const int gw = blockIdx.x * 4 + wid;              // grid 2000 -> 8000 waves

    // register-cache vcat fragment for this lane (reused for 4 rows)
    float4 xv[8];
#pragma unroll
    for (int q = 0; q < 8; ++q) xv[q] = ld4(vcat + q * 256 + lane * 4);

    float lm = -INFINITY, ls = 0.f;
#pragma unroll
    for (int rr = 0; rr < 4; ++rr) {
        const int row = gw * 4 + rr;                  // 8000*4 = 32000 rows
        const float* wr = Wl + (size_t)row * (2 * H);
        float acc = 0.f;
#pragma unroll
        for (int q = 0; q < 8; ++q)
            acc += dot4(ld4(wr + q * 256 + lane * 4), xv[q]);
        acc = waveSum(acc);
        if (lane == 0) {
            float v = acc + bl[row];
            logits[row] = v;
            omerge(lm, ls, v, 1.f);
        }
    }
    __shared__ float2 s2[4];
    if (lane == 0) s2[wid] = make_float2(lm, ls);
    __syncthreads();
    if (t == 0) {
        float M = s2[0].x, S = s2[0].y;
#pragma unroll
        for (int q = 1; q < 4; ++q) omerge(M, S, s2[q].x, s2[q].y);
        part_l[blockIdx.x] = make_float2(M, S);
    }
}

// ============ K6: out = logits - logsumexp (redundant partial reduce) ======
__global__ __launch_bounds__(256) void k_final(
        const float* __restrict__ logits, const float2* __restrict__ part_l,
        float* __restrict__ out) {
    const int t = threadIdx.x, wid = t >> 6, lane = t & 63;
    __shared__ float2 s2[4];
    float m = -INFINITY, s = 0.f;
    for (int i = t; i < 2000; i += 256) {
        float2 p = part_l[i];
        omerge(m, s, p.x, p.y);
    }
    waveOmerge(m, s);
    if (lane == 0) s2[wid] = make_float2(m, s);
    __syncthreads();
    float M = s2[0].x, S = s2[0].y;
#pragma unroll
    for (int q = 1; q < 4; ++q) omerge(M, S, s2[q].x, s2[q].y);
    const float lse = M + logf(S);
    const int i = blockIdx.x * 256 + t;               // 125*256 == 32000
    out[i] = logits[i] - lse;
}

extern "C" void kernel_launch(void* const* d_in, const int* in_sizes, int n_in,
                              void* d_out, int out_size, void* d_ws, size_t ws_size,
                              hipStream_t stream) {
    const int*   widx = (const int*)d_in[0];
    const float* lctx = (const float*)d_in[1];
    const float* h0   = (const float*)d_in[2];
    const float* enc  = (const float*)d_in[3];
    const float* emb  = (const float*)d_in[4];
    const float* W_ih = (const float*)d_in[5];
    const float* W_hh = (const float*)d_in[6];
    const float* b_ih = (const float*)d_in[7];
    const float* b_hh = (const float*)d_in[8];
    const float* Wa   = (const float*)d_in[9];
    // d_in[10] (ba): dropped — constant shift under softmax
    const float* Wl   = (const float*)d_in[11];
    const float* bl   = (const float*)d_in[12];
    float* out = (float*)d_out;
    float* ws  = (float*)d_ws;

    float*  h      = ws;                         // [1024] } vcat = ws[0:2048]
    float*  ctx    = ws + 1024;                  // [1024] }
    float*  u      = ws + 2048;                  // [1024]
    float*  energ  = ws + 3072;                  // [2048]
    float2* part_e = (float2*)(ws + 5120);       // [512]
    float2* part_l = (float2*)(ws + 6144);       // [2000]
    float*  logits = ws + 10240;                 // [32000]

    k_lstm  <<<1024, 256, 0, stream>>>(emb, lctx, h0, W_ih, W_hh, b_ih, b_hh, widx, h, u, ctx);
    k_wa    <<<dim3(4, 32), 256, 0, stream>>>(Wa, h, u);
    k_energy<<<512, 256, 0, stream>>>(enc, u, energ, part_e);
    k_ctx   <<<128, 256, 0, stream>>>(enc, energ, part_e, ctx);
    k_logits<<<2000, 256, 0, stream>>>(Wl, ws /*vcat*/, bl, logits, part_l);
    k_final <<<125, 256, 0, stream>>>(logits, part_l, out);
}

// Round 6
// 72.979 us; speedup vs baseline: 15.3091x; 1.0253x over previous
//
#include <hip/hip_runtime.h>
#include <hip/hip_bf16.h>
#include <math.h>

#define SEQ   2048
#define H     1024
#define VOCAB 32000
#define GRID2 2048
#define NTHR  256

__device__ inline float4 ld4(const float* p) { return *reinterpret_cast<const float4*>(p); }
__device__ inline float dot4(float4 a, float4 b) { return a.x*b.x + a.y*b.y + a.z*b.z + a.w*b.w; }
__device__ inline float sigmoidf(float x) { return 1.f / (1.f + expf(-x)); }

__device__ inline void omerge(float& m, float& s, float m2, float s2) {
    if (m2 > m) { s = s * __expf(m - m2) + s2; m = m2; }
    else if (s2 != 0.f) { s += s2 * __expf(m2 - m); }
}
__device__ inline float waveSum(float v) {
#pragma unroll
    for (int off = 32; off > 0; off >>= 1) v += __shfl_down(v, off, 64);
    return v;
}
__device__ inline void waveOmerge(float& m, float& s) {
#pragma unroll
    for (int off = 32; off > 0; off >>= 1) {
        float m2 = __shfl_down(m, off, 64), ss = __shfl_down(s, off, 64);
        omerge(m, s, m2, ss);
    }
}

// ---- device-scope block signal/wait (flags are uint counters in ws) -------
__device__ inline void blockSignal(unsigned* f) {
    __syncthreads();                    // all block stores drained (vmcnt=0)
    if (threadIdx.x == 0) {
        __threadfence();                // publish to device scope
        __hip_atomic_fetch_add(f, 1u, __ATOMIC_RELEASE, __HIP_MEMORY_SCOPE_AGENT);
    }
}
__device__ inline void blockWait(unsigned* f, unsigned target) {
    if (threadIdx.x == 0) {
        while (__hip_atomic_load(f, __ATOMIC_ACQUIRE, __HIP_MEMORY_SCOPE_AGENT) < target)
            __builtin_amdgcn_s_sleep(4);
        __threadfence();                // invalidate stale cached lines
    }
    __syncthreads();
}

// ws layout (floats):
//  [0..95]   flags (uint idx 0,16,32,48,64): f_h,f_u,f_e,f_ctx,f_l
//  h    = ws+96   [1024]   } vcat contiguous
//  ctx  = ws+1120 [1024]   }
//  u    = ws+2144 [1024]
//  energ= ws+3168 [2048]
//  part_e = (float2*)(ws+5216) [256]
//  part_l = (float2*)(ws+5728) [1792]

__global__ __launch_bounds__(NTHR) void k_init(float* __restrict__ ws) {
    const int t = threadIdx.x;
    unsigned* fl = (unsigned*)ws;
    if (t < 96) fl[t] = 0u;
    float* u   = ws + 2144;
    float* ctx = ws + 1120;
    for (int k = t; k < H; k += NTHR) { u[k] = 0.f; ctx[k] = 0.f; }
}

__global__ __launch_bounds__(NTHR, 8) void k_main(
        const float* __restrict__ emb,  const float* __restrict__ lctx,
        const float* __restrict__ h0,   const float* __restrict__ W_ih,
        const float* __restrict__ W_hh, const float* __restrict__ b_ih,
        const float* __restrict__ b_hh, const int* __restrict__ widx,
        const float* __restrict__ enc,  const float* __restrict__ Wa,
        const float* __restrict__ Wl,   const float* __restrict__ bl,
        float* __restrict__ ws, float* __restrict__ out) {
    const int bid = blockIdx.x, t = threadIdx.x;
    const int wid = t >> 6, lane = t & 63;

    unsigned* f_h   = (unsigned*)ws + 0;
    unsigned* f_u   = (unsigned*)ws + 16;
    unsigned* f_e   = (unsigned*)ws + 32;
    unsigned* f_ctx = (unsigned*)ws + 48;
    unsigned* f_l   = (unsigned*)ws + 64;
    float*  h      = ws + 96;
    float*  ctx    = ws + 1120;
    float*  u      = ws + 2144;
    float*  energ  = ws + 3168;
    float2* part_e = (float2*)(ws + 5216);
    float2* part_l = (float2*)(ws + 5728);

    __shared__ float  lg[12];
    __shared__ float  shh[16];
    __shared__ float  se[8];
    __shared__ float  shw[32];
    __shared__ float2 s2[4];

    // ======== P1: LSTM — blocks 1024..2047, one block per output j ========
    if (bid >= 1024) {
        const int j = bid - 1024;
        const int w = widx[0];                    // int64 LE, value < 32000
        const float* xe = emb + (size_t)w * H;
        const float* wi = W_ih + (size_t)j * (2 * H);
        const float* wg = W_ih + (size_t)(j + 2 * H) * (2 * H);
        const float* wo = W_ih + (size_t)(j + 3 * H) * (2 * H);
        const float* vi = W_hh + (size_t)j * H;
        const float* vg = W_hh + (size_t)(j + 2 * H) * H;
        const float* vo = W_hh + (size_t)(j + 3 * H) * H;
        const int e = t * 4;
        float4 x0 = ld4(xe + e), x1 = ld4(lctx + e), x2 = ld4(h0 + e);
        float ai = dot4(ld4(wi + e), x0) + dot4(ld4(wi + H + e), x1) + dot4(ld4(vi + e), x2);
        float ag = dot4(ld4(wg + e), x0) + dot4(ld4(wg + H + e), x1) + dot4(ld4(vg + e), x2);
        float ao = dot4(ld4(wo + e), x0) + dot4(ld4(wo + H + e), x1) + dot4(ld4(vo + e), x2);
        ai = waveSum(ai); ag = waveSum(ag); ao = waveSum(ao);
        if (lane == 0) { lg[wid*3] = ai; lg[wid*3+1] = ag; lg[wid*3+2] = ao; }
        __syncthreads();
        if (t == 0) {
            float gi = 0.f, gg = 0.f, go = 0.f;
            for (int q = 0; q < 4; ++q) { gi += lg[q*3]; gg += lg[q*3+1]; go += lg[q*3+2]; }
            gi += b_ih[j] + b_hh[j];
            gg += b_ih[j + 2*H] + b_hh[j + 2*H];
            go += b_ih[j + 3*H] + b_hh[j + 3*H];
            float c = sigmoidf(gi) * tanhf(gg);   // c0 == 0 -> f-gate dead
            h[j] = sigmoidf(go) * tanhf(c);
        }
        blockSignal(f_h);
    }

    blockWait(f_h, 1024);   // ---- h complete ----

    if (bid < 256) {
        // ======== attention chain (hidden under the Wl_h stream) ==========
        // --- u = Wa^T h : 64 rowgroups x 16 rows, 4 col slices ---
        {
            const int rg = bid >> 2, kb = bid & 3;
            if (t < 16) shh[t] = h[rg * 16 + t];
            __syncthreads();
            const int k = kb * 256 + t;
            float acc = 0.f;
#pragma unroll
            for (int jj = 0; jj < 16; ++jj)
                acc += Wa[(size_t)(rg * 16 + jj) * H + k] * shh[jj];
            atomicAdd(&u[k], acc);
            blockSignal(f_u);
            blockWait(f_u, 256);
        }
        // --- energies: 8 rows/block (2 per wave) + block (m,s) partial ---
        {
#pragma unroll
            for (int rr = 0; rr < 2; ++rr) {
                const int row = bid * 8 + wid * 2 + rr;
                const float* er = enc + (size_t)row * H;
                float acc = 0.f;
#pragma unroll
                for (int it = 0; it < 4; ++it) {
                    const int e = it * 256 + lane * 4;
                    acc += dot4(ld4(er + e), ld4(u + e));
                }
                acc = waveSum(acc);
                if (lane == 0) { energ[row] = acc; se[wid * 2 + rr] = acc; }
            }
            __syncthreads();
            if (t == 0) {
                float m = -INFINITY, s = 0.f;
                for (int q = 0; q < 8; ++q) omerge(m, s, se[q], 1.f);
                part_e[bid] = make_float2(m, s);
            }
            blockSignal(f_e);
            blockWait(f_e, 256);
        }
        // --- ctx = softmax(energ) @ enc : 64 rowgroups x 32 rows ---
        {
            float2 p = part_e[t];                  // t < 256 reads all partials
            float m = p.x, s = p.y;
            waveOmerge(m, s);
            if (lane == 0) s2[wid] = make_float2(m, s);
            __syncthreads();
            float M = s2[0].x, S = s2[0].y;
#pragma unroll
            for (int q = 1; q < 4; ++q) omerge(M, S, s2[q].x, s2[q].y);
            const float invS = 1.f / S;
            const int rg = bid >> 2, kb = bid & 3;
            __syncthreads();
            if (t < 32) shw[t] = __expf(energ[rg * 32 + t] - M) * invS;
            __syncthreads();
            const int k = kb * 256 + t;
            float acc = 0.f;
#pragma unroll
            for (int jj = 0; jj < 32; ++jj)
                acc += shw[jj] * enc[(size_t)(rg * 32 + jj) * H + k];
            atomicAdd(&ctx[k], acc);
            blockSignal(f_ctx);
        }
        // ======== final: out = logits - lse (blocks 0..124) ===============
        if (bid < 125) {
            blockWait(f_l, 1792);
            float m = -INFINITY, s = 0.f;
            for (int i = t; i < 1792; i += NTHR) {
                float2 p = part_l[i];
                omerge(m, s, p.x, p.y);
            }
            waveOmerge(m, s);
            __syncthreads();
            if (lane == 0) s2[wid] = make_float2(m, s);
            __syncthreads();
            float M = s2[0].x, S = s2[0].y;
#pragma unroll
            for (int q = 1; q < 4; ++q) omerge(M, S, s2[q].x, s2[q].y);
            const float lse = M + logf(S);
            const int i = bid * 256 + t;           // 125*256 == 32000
            out[i] = out[i] - lse;
        }
    } else {
        // ======== streamers: Wl h-half, then ctx-half =====================
        const int gwS = (bid - 256) * 4 + wid;     // 0..7167
        const int NR = (gwS < 3328) ? 5 : 4;       // rows r = gwS + 7168*rr
        float4 xv[4];
#pragma unroll
        for (int q = 0; q < 4; ++q) xv[q] = ld4(h + q * 256 + lane * 4);
        float acc[5] = {0.f, 0.f, 0.f, 0.f, 0.f};
#pragma unroll
        for (int rr = 0; rr < 5; ++rr) {
            if (rr < NR) {
                const float* wr = Wl + (size_t)(gwS + 7168 * rr) * (2 * H);
                float a = 0.f;
#pragma unroll
                for (int q = 0; q < 4; ++q)
                    a += dot4(ld4(wr + q * 256 + lane * 4), xv[q]);
                acc[rr] = a;
            }
        }
        blockWait(f_ctx, 256);   // ---- ctx ready (usually already) ----
#pragma unroll
        for (int q = 0; q < 4; ++q) xv[q] = ld4(ctx + q * 256 + lane * 4);
        float lm = -INFINITY, ls = 0.f;
#pragma unroll
        for (int rr = 0; rr < 5; ++rr) {
            if (rr < NR) {
                const int r = gwS + 7168 * rr;
                const float* wr = Wl + (size_t)r * (2 * H) + H;
                float a = acc[rr];
#pragma unroll
                for (int q = 0; q < 4; ++q)
                    a += dot4(ld4(wr + q * 256 + lane * 4), xv[q]);
                a = waveSum(a);
                if (lane == 0) {
                    float v = a + bl[r];
                    out[r] = v;                    // pre-lse logits staged in out
                    omerge(lm, ls, v, 1.f);
                }
            }
        }
        if (lane == 0) s2[wid] = make_float2(lm, ls);
        __syncthreads();
        if (t == 0) {
            float M = s2[0].x, S = s2[0].y;
#pragma unroll
            for (int q = 1; q < 4; ++q) omerge(M, S, s2[q].x, s2[q].y);
            part_l[bid - 256] = make_float2(M, S);
        }
        blockSignal(f_l);
    }
}

// ======================= fallback path (round-5, proven 74.8 µs) ===========

__global__ __launch_bounds__(256) void k_lstm(
        const float* __restrict__ emb, const float* __restrict__ lctx,
        const float* __restrict__ h0,  const float* __restrict__ W_ih,
        const float* __restrict__ W_hh, const float* __restrict__ b_ih,
        const float* __restrict__ b_hh, const int* __restrict__ widx,
        float* __restrict__ h_out, float* __restrict__ u_zero,
        float* __restrict__ ctx_zero) {
    const int j = blockIdx.x, t = threadIdx.x;
    const int wid = t >> 6, lane = t & 63;
    if (j == 0) for (int k = t; k < H; k += 256) u_zero[k] = 0.f;
    if (j == 1) for (int k = t; k < H; k += 256) ctx_zero[k] = 0.f;
    const int w = widx[0];
    const float* embrow = emb + (size_t)w * H;
    const int ri = j, rg = j + 2 * H, ro = j + 3 * H;
    const float* wi_i = W_ih + (size_t)ri * (2 * H);
    const float* wi_g = W_ih + (size_t)rg * (2 * H);
    const float* wi_o = W_ih + (size_t)ro * (2 * H);
    const float* wh_i = W_hh + (size_t)ri * H;
    const float* wh_g = W_hh + (size_t)rg * H;
    const float* wh_o = W_hh + (size_t)ro * H;
    float ai = 0.f, ag = 0.f, ao = 0.f;
    { int e = t*4; float4 x = ld4(embrow+e);
      ai += dot4(ld4(wi_i+e),x); ag += dot4(ld4(wi_g+e),x); ao += dot4(ld4(wi_o+e),x); }
    { int e = t*4; float4 x = ld4(lctx+e);
      ai += dot4(ld4(wi_i+H+e),x); ag += dot4(ld4(wi_g+H+e),x); ao += dot4(ld4(wi_o+H+e),x); }
    { int e = t*4; float4 x = ld4(h0+e);
      ai += dot4(ld4(wh_i+e),x); ag += dot4(ld4(wh_g+e),x); ao += dot4(ld4(wh_o+e),x); }
    ai = waveSum(ai); ag = waveSum(ag); ao = waveSum(ao);
    __shared__ float lds[12];
    if (lane == 0) { lds[wid*3] = ai; lds[wid*3+1] = ag; lds[wid*3+2] = ao; }
    __syncthreads();
    if (t == 0) {
        float gi = 0.f, gg = 0.f, go = 0.f;
        for (int q = 0; q < 4; ++q) { gi += lds[q*3]; gg += lds[q*3+1]; go += lds[q*3+2]; }
        gi += b_ih[ri] + b_hh[ri];
        gg += b_ih[rg] + b_hh[rg];
        go += b_ih[ro] + b_hh[ro];
        float c = sigmoidf(gi) * tanhf(gg);
        h_out[j] = sigmoidf(go) * tanhf(c);
    }
}

__global__ __launch_bounds__(256) void k_wa(
        const float* __restrict__ Wa, const float* __restrict__ h,
        float* __restrict__ u) {
    const int k = blockIdx.x * 256 + threadIdx.x;
    const int j0 = blockIdx.y * 32;
    float acc = 0.f;
#pragma unroll 8
    for (int j = j0; j < j0 + 32; ++j) acc += Wa[(size_t)j * H + k] * h[j];
    atomicAdd(&u[k], acc);
}

__global__ __launch_bounds__(256) void k_energy(
        const float* __restrict__ enc, const float* __restrict__ u,
        float* __restrict__ energ, float2* __restrict__ part_e) {
    const int t = threadIdx.x, wid = t >> 6, lane = t & 63;
    const int row = blockIdx.x * 4 + wid;
    const float* er = enc + (size_t)row * H;
    float acc = 0.f;
#pragma unroll
    for (int it = 0; it < 4; ++it) { int e = it*256 + lane*4; acc += dot4(ld4(er+e), ld4(u+e)); }
    acc = waveSum(acc);
    __shared__ float se[4];
    if (lane == 0) { energ[row] = acc; se[wid] = acc; }
    __syncthreads();
    if (t == 0) {
        float m = fmaxf(fmaxf(se[0], se[1]), fmaxf(se[2], se[3]));
        float s = __expf(se[0]-m) + __expf(se[1]-m) + __expf(se[2]-m) + __expf(se[3]-m);
        part_e[blockIdx.x] = make_float2(m, s);
    }
}

__global__ __launch_bounds__(256) void k_ctx(
        const float* __restrict__ enc, const float* __restrict__ energ,
        const float2* __restrict__ part_e, float* __restrict__ ctx) {
    const int t = threadIdx.x, wid = t >> 6, lane = t & 63;
    __shared__ float2 s2[4];
    __shared__ float sh[64];
    float2 a = part_e[t], b = part_e[t + 256];
    float m = a.x, s = a.y;
    omerge(m, s, b.x, b.y);
    waveOmerge(m, s);
    if (lane == 0) s2[wid] = make_float2(m, s);
    __syncthreads();
    float M = s2[0].x, S = s2[0].y;
#pragma unroll
    for (int q = 1; q < 4; ++q) omerge(M, S, s2[q].x, s2[q].y);
    const float invS = 1.f / S;
    const int j0 = (blockIdx.x >> 2) * 64;
    __syncthreads();
    if (t < 64) sh[t] = __expf(energ[j0 + t] - M) * invS;
    __syncthreads();
    const int k = (blockIdx.x & 3) * 256 + t;
    float acc = 0.f;
#pragma unroll 8
    for (int jj = 0; jj < 64; ++jj) acc += sh[jj] * enc[(size_t)(j0 + jj) * H + k];
    atomicAdd(&ctx[k], acc);
}

__global__ __launch_bounds__(256) void k_logits(
        const float* __restrict__ Wl, const float* __restrict__ vcat,
        const float* __restrict__ bl, float* __restrict__ logits,
        float2* __restrict__ part_l) {
    const int t = threadIdx.x, wid = t >> 6, lane = t & 63;
    const int gw = blockIdx.x * 4 + wid;
    float4 xv[8];
#pragma unroll
    for (int q = 0; q < 8; ++q) xv[q] = ld4(vcat + q * 256 + lane * 4);
    float lm = -INFINITY, ls = 0.f;
#pragma unroll
    for (int rr = 0; rr < 4; ++rr) {
        const int row = gw * 4 + rr;
        const float* wr = Wl + (size_t)row * (2 * H);
        float acc = 0.f;
#pragma unroll
        for (int q = 0; q < 8; ++q)
            acc += dot4(ld4(wr + q * 256 + lane * 4), xv[q]);
        acc = waveSum(acc);
        if (lane == 0) {
            float v = acc + bl[row];
            logits[row] = v;
            omerge(lm, ls, v, 1.f);
        }
    }
    __shared__ float2 s2[4];
    if (lane == 0) s2[wid] = make_float2(lm, ls);
    __syncthreads();
    if (t == 0) {
        float M = s2[0].x, S = s2[0].y;
#pragma unroll
        for (int q = 1; q < 4; ++q) omerge(M, S, s2[q].x, s2[q].y);
        part_l[blockIdx.x] = make_float2(M, S);
    }
}

__global__ __launch_bounds__(256) void k_final(
        const float* __restrict__ logits, const float2* __restrict__ part_l,
        float* __restrict__ out) {
    const int t = threadIdx.x, wid = t >> 6, lane = t & 63;
    __shared__ float2 s2[4];
    float m = -INFINITY, s = 0.f;
    for (int i = t; i < 2000; i += 256) {
        float2 p = part_l[i];
        omerge(m, s, p.x, p.y);
    }
    waveOmerge(m, s);
    if (lane == 0) s2[wid] = make_float2(m, s);
    __syncthreads();
    float M = s2[0].x, S = s2[0].y;
#pragma unroll
    for (int q = 1; q < 4; ++q) omerge(M, S, s2[q].x, s2[q].y);
    const float lse = M + logf(S);
    const int i = blockIdx.x * 256 + t;
    out[i] = logits[i] - lse;
}

extern "C" void kernel_launch(void* const* d_in, const int* in_sizes, int n_in,
                              void* d_out, int out_size, void* d_ws, size_t ws_size,
                              hipStream_t stream) {
    const int*   widx = (const int*)d_in[0];
    const float* lctx = (const float*)d_in[1];
    const float* h0   = (const float*)d_in[2];
    const float* enc  = (const float*)d_in[3];
    const float* emb  = (const float*)d_in[4];
    const float* W_ih = (const float*)d_in[5];
    const float* W_hh = (const float*)d_in[6];
    const float* b_ih = (const float*)d_in[7];
    const float* b_hh = (const float*)d_in[8];
    const float* Wa   = (const float*)d_in[9];
    // d_in[10] (ba): dropped — constant shift under softmax
    const float* Wl   = (const float*)d_in[11];
    const float* bl   = (const float*)d_in[12];
    float* out = (float*)d_out;
    float* ws  = (float*)d_ws;

    // deadlock guard: persistent path requires all GRID2 blocks co-resident
    int occ = 0, nCU = 0, dev = 0;
    hipGetDevice(&dev);
    hipDeviceGetAttribute(&nCU, hipDeviceAttributeMultiprocessorCount, dev);
    hipError_t oe = hipOccupancyMaxActiveBlocksPerMultiprocessor(
        &occ, (const void*)k_main, NTHR, 0);
    const bool persistent_ok = (oe == hipSuccess) && ((long)occ * nCU >= GRID2);

    if (persistent_ok) {
        k_init<<<1, NTHR, 0, stream>>>(ws);
        k_main<<<GRID2, NTHR, 0, stream>>>(emb, lctx, h0, W_ih, W_hh, b_ih,
                                           b_hh, widx, enc, Wa, Wl, bl, ws, out);
    } else {
        float*  h      = ws;
        float*  ctx    = ws + 1024;
        float*  u      = ws + 2048;
        float*  energ  = ws + 3072;
        float2* part_e = (float2*)(ws + 5120);
        float2* part_l = (float2*)(ws + 6144);
        float*  logits = ws + 10240;
        k_lstm  <<<1024, 256, 0, stream>>>(emb, lctx, h0, W_ih, W_hh, b_ih, b_hh, widx, h, u, ctx);
        k_wa    <<<dim3(4, 32), 256, 0, stream>>>(Wa, h, u);
        k_energy<<<512, 256, 0, stream>>>(enc, u, energ, part_e);
        k_ctx   <<<128, 256, 0, stream>>>(enc, energ, part_e, ctx);
        k_logits<<<2000, 256, 0, stream>>>(Wl, ws /*vcat*/, bl, logits, part_l);
        k_final <<<125, 256, 0, stream>>>(logits, part_l, out);
    }
}